// Round 5
// baseline (828.772 us; speedup 1.0000x reference)
//
#include <hip/hip_runtime.h>
#include <math.h>

#define HID 256

typedef __bf16 bf16_t;
typedef __attribute__((ext_vector_type(8))) __bf16 bf16x8;
typedef __attribute__((ext_vector_type(4))) __bf16 bf16x4;
typedef __attribute__((ext_vector_type(4))) float f32x4;

__device__ __forceinline__ float gelu_f(float x){
  return 0.5f * x * (1.0f + erff(x * 0.70710678118654752440f));
}

// ---------------- bf16 MFMA NT GEMM: C = epi(A[M,K] @ Bt[N,K]^T + bias) ----------------
// mode: 0 plain->bf16, 1 relu->bf16, 2 qscale->bf16, 3 skipblend->bf16, 4 sigmoid->f32
// a_f32: A is fp32 (converted to bf16 during LDS staging)
__global__ __launch_bounds__(256) void mfma_gemm_k(
    const void* __restrict__ A, int lda,
    const bf16_t* __restrict__ Bt, int ldb,
    const float* __restrict__ bias,
    void* __restrict__ Cout, int ldc,
    int M, int N, int K,
    int mode, int a_gelu, int a_f32,
    const int* __restrict__ a_rows,
    const float* __restrict__ pvec,
    const bf16_t* __restrict__ skipx,
    const float* __restrict__ skip_gate)
{
  constexpr int LDSS = 72;   // 64 + 8 pad (16B) breaks 128B-stride bank aliasing
  __shared__ bf16_t As[128*LDSS];
  __shared__ bf16_t Bs[128*LDSS];
  const int t = threadIdx.x;
  const int wave = t >> 6, lane = t & 63;
  const int quad = lane >> 4, l16 = lane & 15;
  const int row0 = blockIdx.y*128, col0 = blockIdx.x*128;
  const int R = (wave>>1)*64, Cb = (wave&1)*64;
  f32x4 acc[4][4] = {};

  for (int k0 = 0; k0 < K; k0 += 64){
#pragma unroll
    for (int i = 0; i < 4; i++){
      int id = t + i*256;
      int r = id >> 3, c = (id & 7)*8;
      int gr = row0 + r;
      bf16x8 v = {};
      if (gr < M){
        int ar = a_rows ? a_rows[gr] : gr;
        if (a_f32){
          const float* p = (const float*)A + (long long)ar*lda + k0 + c;
          float4 f0 = *(const float4*)p;
          float4 f1 = *(const float4*)(p + 4);
          v[0]=(bf16_t)f0.x; v[1]=(bf16_t)f0.y; v[2]=(bf16_t)f0.z; v[3]=(bf16_t)f0.w;
          v[4]=(bf16_t)f1.x; v[5]=(bf16_t)f1.y; v[6]=(bf16_t)f1.z; v[7]=(bf16_t)f1.w;
        } else {
          v = *(const bf16x8*)((const bf16_t*)A + (long long)ar*lda + k0 + c);
          if (a_gelu){
#pragma unroll
            for (int j = 0; j < 8; j++) v[j] = (bf16_t)gelu_f((float)v[j]);
          }
        }
      }
      *(bf16x8*)(As + r*LDSS + c) = v;
    }
#pragma unroll
    for (int i = 0; i < 4; i++){
      int id = t + i*256;
      int r = id >> 3, c = (id & 7)*8;
      int gc = col0 + r;
      bf16x8 v = {};
      if (gc < N) v = *(const bf16x8*)(Bt + (long long)gc*ldb + k0 + c);
      *(bf16x8*)(Bs + r*LDSS + c) = v;
    }
    __syncthreads();
#pragma unroll
    for (int kk = 0; kk < 64; kk += 32){
      bf16x8 af[4], bfr[4];
#pragma unroll
      for (int i = 0; i < 4; i++) af[i]  = *(const bf16x8*)(As + (R  + 16*i + l16)*LDSS + kk + quad*8);
#pragma unroll
      for (int j = 0; j < 4; j++) bfr[j] = *(const bf16x8*)(Bs + (Cb + 16*j + l16)*LDSS + kk + quad*8);
#pragma unroll
      for (int i = 0; i < 4; i++)
#pragma unroll
        for (int j = 0; j < 4; j++)
          acc[i][j] = __builtin_amdgcn_mfma_f32_16x16x32_bf16(af[i], bfr[j], acc[i][j], 0, 0, 0);
    }
    __syncthreads();
  }

  float gate = 0.f;
  if (mode == 3) gate = 1.f/(1.f + expf(-(*skip_gate)));
#pragma unroll
  for (int i = 0; i < 4; i++){
#pragma unroll
    for (int j = 0; j < 4; j++){
#pragma unroll
      for (int r = 0; r < 4; r++){
        int gr = row0 + R + 16*i + quad*4 + r;
        int gc = col0 + Cb + 16*j + l16;
        if (gr >= M || gc >= N) continue;
        float v = acc[i][j][r] + (bias ? bias[gc] : 0.f);
        if (mode == 1) v = fmaxf(v, 0.f);
        else if (mode == 2) v *= pvec[gc >> 7] * 0.08838834764831845f;
        else if (mode == 3) v = gate*v + (1.f - gate)*(float)skipx[(long long)gr*HID + gc];
        if (mode == 4) ((float*)Cout)[(long long)gr*ldc + gc] = 1.f/(1.f + expf(-v));
        else ((bf16_t*)Cout)[(long long)gr*ldc + gc] = (bf16_t)v;
      }
    }
  }
}

// ---------------- fused weight transpose+cast: W[K,N](lda) fp32 -> Wt[N,K] bf16 ----------------
struct TW { const float* W; bf16_t* out; int lda; int K; int N; };

__global__ __launch_bounds__(256) void prep_weights_k(TW w0, TW w1, TW w2, TW w3, TW w4){
  TW tw;
  switch (blockIdx.z){
    case 0: tw = w0; break; case 1: tw = w1; break; case 2: tw = w2; break;
    case 3: tw = w3; break; default: tw = w4; break;
  }
  __shared__ float tile[32][33];
  int bx = blockIdx.x*32, by = blockIdx.y*32;
  if (by >= tw.K || bx >= tw.N) return;
  int tx = threadIdx.x, ty = threadIdx.y;
  for (int i = 0; i < 32; i += 8){
    int k = by + ty + i, n = bx + tx;
    tile[ty+i][tx] = (k < tw.K && n < tw.N) ? tw.W[(long long)k*tw.lda + n] : 0.f;
  }
  __syncthreads();
  for (int i = 0; i < 32; i += 8){
    int n = bx + ty + i, k = by + tx;
    if (n < tw.N && k < tw.K) tw.out[(long long)n*tw.K + k] = (bf16_t)tile[tx][ty+i];
  }
}

// ---------------- fold Wk_rel/Wv_rel into kqv_p weights, output transposed bf16 ----------------
// Wkvt[n'][m] = sum_k Wkqv_p[m, off + k] * rel[h, k, n],  n' = kv*256 + h*128 + n, off = kv*512 + h*128
// bkv[n'] = sum_k bkqv_p[off + k] * rel[h, k, n]
__global__ __launch_bounds__(256) void prep_fold_k(
    const float* __restrict__ Wkqv_p, const float* __restrict__ bkqv_p,
    const float* __restrict__ Wk_rel, const float* __restrict__ Wv_rel,
    bf16_t* __restrict__ Wkvt, float* __restrict__ bkv)
{
  int np = blockIdx.x;            // 0..511
  int kv = np >> 8, h = (np >> 7) & 1, n = np & 127;
  int off = kv*512 + h*128;
  const float* rel = (kv ? Wv_rel : Wk_rel) + h*128*128 + n;  // column n, stride 128
  __shared__ float relcol[128];
  int t = threadIdx.x;
  if (t < 128) relcol[t] = rel[t*128];
  __syncthreads();
  int m = t;                      // 0..255
  const float* wp = Wkqv_p + (long long)m*768 + off;
  float acc = 0.f;
#pragma unroll 8
  for (int k = 0; k < 128; k++) acc += wp[k] * relcol[k];
  Wkvt[(long long)np*256 + m] = (bf16_t)acc;
  if (t == 0){
    float b = 0.f;
    for (int k = 0; k < 128; k++) b += bkqv_p[off + k] * relcol[k];
    bkv[np] = b;
  }
}

// ---------------- CSR build ----------------
__global__ void hist_k(const int* __restrict__ dst, int E, int* __restrict__ deg){
  int i = blockIdx.x*256 + threadIdx.x;
  if (i < E) atomicAdd(&deg[dst[i]], 1);
}

__global__ __launch_bounds__(256) void partial_sum_k(
    const int* __restrict__ deg, int n, int* __restrict__ part)
{
  __shared__ int sdata[4];
  int i = blockIdx.x*256 + threadIdx.x;
  int v = (i < n) ? deg[i] : 0;
#pragma unroll
  for (int o = 32; o; o >>= 1) v += __shfl_xor(v, o);
  int lane = threadIdx.x & 63, wid = threadIdx.x >> 6;
  if (lane == 0) sdata[wid] = v;
  __syncthreads();
  if (threadIdx.x == 0) part[blockIdx.x] = sdata[0]+sdata[1]+sdata[2]+sdata[3];
}

__global__ __launch_bounds__(256) void scan_part_k(
    int* __restrict__ part, int nb, int* __restrict__ total_out)
{
  __shared__ int ws[4]; __shared__ int tot;
  int t = threadIdx.x;
  int v = (t < nb) ? part[t] : 0;
  int lane = t & 63, wid = t >> 6;
  int x = v;
#pragma unroll
  for (int o = 1; o < 64; o <<= 1){ int y = __shfl_up(x, o); if (lane >= o) x += y; }
  if (lane == 63) ws[wid] = x;
  __syncthreads();
  if (t == 0){ int s = 0; for (int i = 0; i < 4; i++){ int tmp = ws[i]; ws[i] = s; s += tmp; } tot = s; }
  __syncthreads();
  int excl = x - v + ws[wid];
  if (t < nb) part[t] = excl;
  if (t == 0) *total_out = tot;
}

__global__ __launch_bounds__(256) void scan_offs_k(
    const int* __restrict__ deg, int n, const int* __restrict__ part,
    int* __restrict__ offs, int* __restrict__ cursor)
{
  __shared__ int ws[4];
  int t = threadIdx.x;
  int i = blockIdx.x*256 + t;
  int v = (i < n) ? deg[i] : 0;
  int lane = t & 63, wid = t >> 6;
  int x = v;
#pragma unroll
  for (int o = 1; o < 64; o <<= 1){ int y = __shfl_up(x, o); if (lane >= o) x += y; }
  if (lane == 63) ws[wid] = x;
  __syncthreads();
  int pre = 0;
  for (int k = 0; k < wid; k++) pre += ws[k];
  if (i < n){ int o = part[blockIdx.x] + x - v + pre; offs[i] = o; cursor[i] = o; }
}

__global__ void scatter_k(const int* __restrict__ src, const int* __restrict__ dst, int E,
                          int* __restrict__ cursor, int* __restrict__ esrc){
  int i = blockIdx.x*256 + threadIdx.x;
  if (i < E){
    int s = src[i], d = dst[i];
    int p = atomicAdd(&cursor[d], 1);
    esrc[p] = s;
  }
}

// ---------------- fused attention: one wave per dst, 8 edges per batch ----------------
// Edge indices preloaded into registers (coalesced, one per lane), fetched via __shfl.
// Batch of 4 pair-slots (8 edges): 8 row-loads issue together, 4 independent dot chains,
// then the 4 shuffle-reduce chains run INTERLEAVED (4 independent ds ops per level) so the
// ~4x30cy serial reduce latency is paid once per 8 edges instead of once per 2. This
// parallelism is enforced by data flow, not scheduling hints.
// Half-wave h processes pair-member h; lane hl covers elems hl*8..hl*8+7 (lanes 0-15 head0).
__global__ __launch_bounds__(256) void attn_fused_k(
    const bf16_t* __restrict__ q, const bf16_t* __restrict__ keve,
    const int* __restrict__ offs, const int* __restrict__ esrc,
    int Na, bf16_t* __restrict__ agg)
{
  int gid = blockIdx.x*256 + threadIdx.x;
  int dst = gid >> 6, lane = gid & 63;
  if (dst >= Na) return;
  const int hl = lane & 31;       // position within half-wave
  const int half = lane >> 5;     // which member of the edge pair
  bf16x8 qv = *(const bf16x8*)(q + (size_t)dst*256 + hl*8);
  float qf[8];
#pragma unroll
  for (int j = 0; j < 8; j++) qf[j] = (float)qv[j];
  int beg = offs[dst], end = offs[dst+1];
  int cnt = end - beg;
  int cap = cnt < 64 ? cnt : 64;
  int myidx = 0;
  if (cnt > 0) myidx = esrc[beg + (lane < cnt ? lane : cnt - 1)];   // coalesced preload
  float n[8] = {};
  float den = 0.f;

  int npairs = cap >> 1;
  int it = 0;
  for (; it + 4 <= npairs; it += 4){
    int es0 = __shfl(myidx, 2*it     + half);
    int es1 = __shfl(myidx, 2*it + 2 + half);
    int es2 = __shfl(myidx, 2*it + 4 + half);
    int es3 = __shfl(myidx, 2*it + 6 + half);
    const bf16_t* r0 = keve + ((size_t)(unsigned)es0 << 9);
    const bf16_t* r1 = keve + ((size_t)(unsigned)es1 << 9);
    const bf16_t* r2 = keve + ((size_t)(unsigned)es2 << 9);
    const bf16_t* r3 = keve + ((size_t)(unsigned)es3 << 9);
    bf16x8 k0 = *(const bf16x8*)(r0 + hl*8);
    bf16x8 k1 = *(const bf16x8*)(r1 + hl*8);
    bf16x8 k2 = *(const bf16x8*)(r2 + hl*8);
    bf16x8 k3 = *(const bf16x8*)(r3 + hl*8);
    bf16x8 v0 = *(const bf16x8*)(r0 + 256 + hl*8);
    bf16x8 v1 = *(const bf16x8*)(r1 + 256 + hl*8);
    bf16x8 v2 = *(const bf16x8*)(r2 + 256 + hl*8);
    bf16x8 v3 = *(const bf16x8*)(r3 + 256 + hl*8);
    float p0 = 0.f, p1 = 0.f, p2 = 0.f, p3 = 0.f;
#pragma unroll
    for (int j = 0; j < 8; j++){
      p0 += qf[j]*(float)k0[j];
      p1 += qf[j]*(float)k1[j];
      p2 += qf[j]*(float)k2[j];
      p3 += qf[j]*(float)k3[j];
    }
#pragma unroll
    for (int o = 1; o <= 8; o <<= 1){        // 4 interleaved reduce chains
      p0 += __shfl_xor(p0, o);
      p1 += __shfl_xor(p1, o);
      p2 += __shfl_xor(p2, o);
      p3 += __shfl_xor(p3, o);
    }
    float w0 = __expf(p0), w1 = __expf(p1), w2 = __expf(p2), w3 = __expf(p3);
#pragma unroll
    for (int j = 0; j < 8; j++)
      n[j] += w0*(float)v0[j] + w1*(float)v1[j] + w2*(float)v2[j] + w3*(float)v3[j];
    den += w0 + w1 + w2 + w3;
  }
  for (; it < npairs; ++it){       // remainder pairs (0-3)
    int es = __shfl(myidx, 2*it + half);
    const bf16_t* row = keve + ((size_t)(unsigned)es << 9);
    bf16x8 kv = *(const bf16x8*)(row + hl*8);
    bf16x8 vv = *(const bf16x8*)(row + 256 + hl*8);
    float p = qf[0]*(float)kv[0] + qf[1]*(float)kv[1]
            + qf[2]*(float)kv[2] + qf[3]*(float)kv[3]
            + qf[4]*(float)kv[4] + qf[5]*(float)kv[5]
            + qf[6]*(float)kv[6] + qf[7]*(float)kv[7];
    p += __shfl_xor(p, 1); p += __shfl_xor(p, 2);
    p += __shfl_xor(p, 4); p += __shfl_xor(p, 8);
    float wgt = __expf(p);
#pragma unroll
    for (int j = 0; j < 8; j++) n[j] += wgt*(float)vv[j];
    den += wgt;
  }
  if (cap & 1){                   // odd leftover within the register window
    int es = __shfl(myidx, cap - 1);
    const bf16_t* row = keve + ((size_t)(unsigned)es << 9);
    bf16x8 kv = *(const bf16x8*)(row + hl*8);
    bf16x8 vv = *(const bf16x8*)(row + 256 + hl*8);
    float p = qf[0]*(float)kv[0] + qf[1]*(float)kv[1]
            + qf[2]*(float)kv[2] + qf[3]*(float)kv[3]
            + qf[4]*(float)kv[4] + qf[5]*(float)kv[5]
            + qf[6]*(float)kv[6] + qf[7]*(float)kv[7];
    p += __shfl_xor(p, 1); p += __shfl_xor(p, 2);
    p += __shfl_xor(p, 4); p += __shfl_xor(p, 8);
    float wgt = (half == 0) ? __expf(p) : 0.f;      // only half 0 owns this edge
#pragma unroll
    for (int j = 0; j < 8; j++) n[j] += wgt*(float)vv[j];
    den += wgt;
  }
  // ultra-rare tail: degree > 64 (Binomial(800k,1/50k) makes this ~impossible, but be correct)
  for (int i = beg + 64; i < end; i += 2){
    int e2 = i + half;
    int es = esrc[(e2 < end) ? e2 : i];
    const bf16_t* row = keve + ((size_t)(unsigned)es << 9);
    bf16x8 kv = *(const bf16x8*)(row + hl*8);
    bf16x8 vv = *(const bf16x8*)(row + 256 + hl*8);
    float p = qf[0]*(float)kv[0] + qf[1]*(float)kv[1]
            + qf[2]*(float)kv[2] + qf[3]*(float)kv[3]
            + qf[4]*(float)kv[4] + qf[5]*(float)kv[5]
            + qf[6]*(float)kv[6] + qf[7]*(float)kv[7];
    p += __shfl_xor(p, 1); p += __shfl_xor(p, 2);
    p += __shfl_xor(p, 4); p += __shfl_xor(p, 8);
    float wgt = (e2 < end) ? __expf(p) : 0.f;
#pragma unroll
    for (int j = 0; j < 8; j++) n[j] += wgt*(float)vv[j];
    den += wgt;
  }
  // merge the two half-wave edge streams (lane l and l+32 hold identical components)
  den += __shfl_xor(den, 32);
#pragma unroll
  for (int j = 0; j < 8; j++) n[j] += __shfl_xor(n[j], 32);
  if (half == 0){
    float r = 1.f/(den + 1e-16f);
    bf16x8 o;
#pragma unroll
    for (int j = 0; j < 8; j++) o[j] = (bf16_t)(n[j]*r);
    *(bf16x8*)(agg + (size_t)dst*256 + hl*8) = o;
  }
}

extern "C" void kernel_launch(void* const* d_in, const int* in_sizes, int n_in,
                              void* d_out, int out_size, void* d_ws, size_t ws_size,
                              hipStream_t stream)
{
  (void)n_in; (void)out_size; (void)ws_size;
  const float* x_author    = (const float*)d_in[0];
  const float* x_paper     = (const float*)d_in[1];
  const int*   eb_src      = (const int*)d_in[4];
  const int*   eb_dst      = (const int*)d_in[5];
  const int*   input_nodes = (const int*)d_in[6];
  const float* W_in_a  = (const float*)d_in[7];
  const float* b_in_a  = (const float*)d_in[8];
  const float* W_in_p  = (const float*)d_in[9];
  const float* b_in_p  = (const float*)d_in[10];
  const float* Wkqv_a  = (const float*)d_in[11];
  const float* bkqv_a  = (const float*)d_in[12];
  const float* Wkqv_p  = (const float*)d_in[13];
  const float* bkqv_p  = (const float*)d_in[14];
  const float* Wk_rel_b= (const float*)d_in[17];
  const float* Wv_rel_b= (const float*)d_in[18];
  const float* p_b     = (const float*)d_in[20];
  const float* Wout_a  = (const float*)d_in[21];
  const float* bout_a  = (const float*)d_in[22];
  const float* skip_a  = (const float*)d_in[25];
  const float* W_dec   = (const float*)d_in[27];
  const float* b_dec   = (const float*)d_in[28];

  const int Na = in_sizes[0] / 128;
  const int Np = in_sizes[1] / 128;
  const int E  = in_sizes[4];
  const int NI = in_sizes[6];

  char* w = (char*)d_ws;
  auto alloc = [&](size_t bytes)->void*{
    void* p = (void*)w; w += (bytes + 255) & ~(size_t)255; return p;
  };
  bf16_t* xa_bf = (bf16_t*)alloc((size_t)Na*HID*2);
  bf16_t* xp_bf = (bf16_t*)alloc((size_t)Np*HID*2);
  bf16_t* qb    = (bf16_t*)alloc((size_t)Na*HID*2);  // reused as za after attention
  bf16_t* aggb  = (bf16_t*)alloc((size_t)Na*HID*2);
  bf16_t* zin   = (bf16_t*)alloc((size_t)NI*HID*2);
  bf16_t* Wt_in_a = (bf16_t*)alloc(128*HID*2);
  bf16_t* Wt_in_p = (bf16_t*)alloc(128*HID*2);
  bf16_t* Wt_q    = (bf16_t*)alloc(HID*HID*2);
  bf16_t* Wt_out  = (bf16_t*)alloc(HID*HID*2);
  bf16_t* Wt_dec  = (bf16_t*)alloc(HID*HID*2);
  bf16_t* Wkvt    = (bf16_t*)alloc((size_t)512*HID*2);
  float*  bkv     = (float*)alloc(512*4);
  int* deg    = (int*)alloc((size_t)Na*4);
  int* offs   = (int*)alloc((size_t)(Na+1)*4);
  int* cursor = (int*)alloc((size_t)Na*4);
  int* part   = (int*)alloc(1024);
  int* esrc   = (int*)alloc((size_t)E*4);

  // keve [Np,512] bf16 (ke||ve interleaved per row) lives in d_out (51.2 of 102.4 MB),
  // dead before the final GEMM overwrites d_out.
  bf16_t* keve = (bf16_t*)d_out;
  bf16_t* zab  = qb;

  dim3 blk(256);

  // fused weight transposes (fp32 -> bf16, K-major)
  TW tw0 = { W_in_a,       Wt_in_a, 256, 128, 256 };
  TW tw1 = { W_in_p,       Wt_in_p, 256, 128, 256 };
  TW tw2 = { Wkqv_a + 256, Wt_q,    768, 256, 256 };
  TW tw3 = { Wout_a,       Wt_out,  256, 256, 256 };
  TW tw4 = { W_dec,        Wt_dec,  256, 256, 256 };
  prep_weights_k<<<dim3(8,8,5), dim3(32,8), 0, stream>>>(tw0, tw1, tw2, tw3, tw4);
  // fold rel-matrices into kqv_p (transposed bf16 out) + folded bias
  prep_fold_k<<<512, blk, 0, stream>>>(Wkqv_p, bkqv_p, Wk_rel_b, Wv_rel_b, Wkvt, bkv);

  dim3 gNa(2, (Na+127)/128);
  dim3 gNp(2, (Np+127)/128);
  // xa = relu(x_author @ W_in_a + b)   (fp32 A staged directly)
  mfma_gemm_k<<<gNa, blk, 0, stream>>>(x_author, 128, Wt_in_a, 128, b_in_a, xa_bf, HID,
      Na, 256, 128, 1, 0, 1, nullptr, nullptr, nullptr, nullptr);
  // xp = relu(x_paper @ W_in_p + b)
  mfma_gemm_k<<<gNp, blk, 0, stream>>>(x_paper, 128, Wt_in_p, 128, b_in_p, xp_bf, HID,
      Np, 256, 128, 1, 0, 1, nullptr, nullptr, nullptr, nullptr);
  // q = (xa @ Wq + b) * p_b[h]/sqrt(128)
  mfma_gemm_k<<<gNa, blk, 0, stream>>>(xa_bf, HID, Wt_q, HID, bkqv_a + 256, qb, HID,
      Na, 256, 256, 2, 0, 0, nullptr, p_b, nullptr, nullptr);
  // keve = xp @ [Wk_fold || Wv_fold] + [bk||bv]   (N=512, interleaved rows)
  mfma_gemm_k<<<dim3(4,(Np+127)/128), blk, 0, stream>>>(xp_bf, HID, Wkvt, HID, bkv, keve, 512,
      Np, 512, 256, 0, 0, 0, nullptr, nullptr, nullptr, nullptr);
  // CSR over edge_b (dst = authors)
  hipMemsetAsync(deg, 0, (size_t)Na*4, stream);
  hist_k<<<(E+255)/256, blk, 0, stream>>>(eb_dst, E, deg);
  int nb = (Na+255)/256;
  partial_sum_k<<<nb, blk, 0, stream>>>(deg, Na, part);
  scan_part_k<<<1, blk, 0, stream>>>(part, nb, offs+Na);
  scan_offs_k<<<nb, blk, 0, stream>>>(deg, Na, part, offs, cursor);
  scatter_k<<<(E+255)/256, blk, 0, stream>>>(eb_src, eb_dst, E, cursor, esrc);
  // fused attention: logits + softmax + weighted aggregation, 8 edges per batch
  attn_fused_k<<<(Na+3)/4, blk, 0, stream>>>(qb, keve, offs, esrc, Na, aggb);
  // za = g*(gelu(agg)@Wout + b) + (1-g)*xa   (za reuses q buffer)
  mfma_gemm_k<<<gNa, blk, 0, stream>>>(aggb, HID, Wt_out, HID, bout_a, zab, HID,
      Na, 256, 256, 3, 1, 0, nullptr, nullptr, xa_bf, skip_a);
  // zin = za[input_nodes] @ W_dec + b
  mfma_gemm_k<<<dim3(2,(NI+127)/128), blk, 0, stream>>>(zab, HID, Wt_dec, HID, b_dec, zin, HID,
      NI, 256, 256, 0, 0, 0, input_nodes, nullptr, nullptr, nullptr);
  // out = sigmoid(zin @ za^T)  (fp32 out)
  mfma_gemm_k<<<dim3((Na+127)/128, (NI+127)/128), blk, 0, stream>>>(zin, HID, zab, HID, nullptr,
      (float*)d_out, Na, NI, Na, 256, 4, 0, 0, nullptr, nullptr, nullptr, nullptr);
}

// Round 7
// 762.533 us; speedup vs baseline: 1.0869x; 1.0869x over previous
//
#include <hip/hip_runtime.h>
#include <math.h>

#define HID 256

typedef __bf16 bf16_t;
typedef __attribute__((ext_vector_type(8))) __bf16 bf16x8;
typedef __attribute__((ext_vector_type(4))) __bf16 bf16x4;
typedef __attribute__((ext_vector_type(4))) float f32x4;

__device__ __forceinline__ float gelu_f(float x){
  return 0.5f * x * (1.0f + erff(x * 0.70710678118654752440f));
}

// async global->LDS 16B: linear LDS dest (base + lane*16), per-lane global src
__device__ __forceinline__ void gload16(const void* g, void* l){
  __builtin_amdgcn_global_load_lds(
      (const __attribute__((address_space(1))) unsigned int*)g,
      (__attribute__((address_space(3))) unsigned int*)l, 16, 0, 0);
}

// ---------------- bf16 MFMA NT GEMM: C = epi(A[M,K] @ Bt[N,K]^T + bias) ----------------
// mode: 0 plain->bf16, 1 relu->bf16, 2 qscale->bf16, 3 skipblend->bf16, 4 sigmoid->f32
// a_f32: A is fp32 (converted to bf16 during LDS staging, reg-staged path)
// LDS layout: linear [128 rows][64 bf16] per operand, XOR-swizzled 16B chunks:
//   LDS(row, p) holds global chunk p ^ (row&7)  (rule #21: swizzle on BOTH write-src and read)
// bf16 operands stage via global_load_lds (wave-uniform LDS base + lane*16; per-lane src
// address pre-swizzled). fp32/gelu A-paths reg-stage and ds_write to the swizzled chunk.
__global__ __launch_bounds__(256) void mfma_gemm_k(
    const void* __restrict__ A, int lda,
    const bf16_t* __restrict__ Bt, int ldb,
    const float* __restrict__ bias,
    void* __restrict__ Cout, int ldc,
    int M, int N, int K,
    int mode, int a_gelu, int a_f32,
    const int* __restrict__ a_rows,
    const float* __restrict__ pvec,
    const bf16_t* __restrict__ skipx,
    const float* __restrict__ skip_gate)
{
  __shared__ bf16_t As[128*64];
  __shared__ bf16_t Bs[128*64];
  const int t = threadIdx.x;
  const int wave = t >> 6, lane = t & 63;
  const int quad = lane >> 4, l16 = lane & 15;
  const int row0 = blockIdx.y*128, col0 = blockIdx.x*128;
  const int R = (wave>>1)*64, Cb = (wave&1)*64;
  const int lrow = lane >> 3;          // row within 8-row group (0..7)
  const int schunk = (lane & 7) ^ lrow; // pre-swizzled source 16B-chunk index
  const bool a_direct = (!a_f32 && !a_gelu);
  f32x4 acc[4][4] = {};

  for (int k0 = 0; k0 < K; k0 += 64){
    // ---- stage A ----
    if (a_direct){
#pragma unroll
      for (int i = 0; i < 4; i++){
        int r0 = wave*32 + i*8;
        int gr = row0 + r0 + lrow;
        int rr = gr < M ? gr : M-1;           // clamp: finite garbage -> masked rows only
        int ar = a_rows ? a_rows[rr] : rr;
        gload16((const bf16_t*)A + (long long)ar*lda + k0 + schunk*8, As + r0*64);
      }
    } else {
#pragma unroll
      for (int i = 0; i < 4; i++){
        int id = t + i*256;
        int r = id >> 3, c4 = id & 7;
        int gr = row0 + r;
        bf16x8 v = {};
        if (gr < M){
          if (a_f32){
            const float* p = (const float*)A + (long long)gr*lda + k0 + c4*8;
            float4 f0 = *(const float4*)p;
            float4 f1 = *(const float4*)(p + 4);
            v[0]=(bf16_t)f0.x; v[1]=(bf16_t)f0.y; v[2]=(bf16_t)f0.z; v[3]=(bf16_t)f0.w;
            v[4]=(bf16_t)f1.x; v[5]=(bf16_t)f1.y; v[6]=(bf16_t)f1.z; v[7]=(bf16_t)f1.w;
          } else {
            v = *(const bf16x8*)((const bf16_t*)A + (long long)gr*lda + k0 + c4*8);
#pragma unroll
            for (int j = 0; j < 8; j++) v[j] = (bf16_t)gelu_f((float)v[j]);
          }
        }
        *(bf16x8*)(As + r*64 + ((c4 ^ (r&7))*8)) = v;   // write-side swizzle
      }
    }
    // ---- stage B (always bf16) ----
#pragma unroll
    for (int i = 0; i < 4; i++){
      int r0 = wave*32 + i*8;
      int gc = col0 + r0 + lrow;
      int rc = gc < N ? gc : N-1;
      gload16(Bt + (long long)rc*ldb + k0 + schunk*8, Bs + r0*64);
    }
    __syncthreads();
#pragma unroll
    for (int kk = 0; kk < 64; kk += 32){
      const int cb = quad + (kk >> 3);   // logical 16B chunk for this fragment
      bf16x8 af[4], bfr[4];
#pragma unroll
      for (int i = 0; i < 4; i++){
        int row = R + 16*i + l16;
        af[i]  = *(const bf16x8*)(As + row*64 + ((cb ^ (row&7))*8));
      }
#pragma unroll
      for (int j = 0; j < 4; j++){
        int row = Cb + 16*j + l16;
        bfr[j] = *(const bf16x8*)(Bs + row*64 + ((cb ^ (row&7))*8));
      }
#pragma unroll
      for (int i = 0; i < 4; i++)
#pragma unroll
        for (int j = 0; j < 4; j++)
          acc[i][j] = __builtin_amdgcn_mfma_f32_16x16x32_bf16(af[i], bfr[j], acc[i][j], 0, 0, 0);
    }
    __syncthreads();
  }

  float gate = 0.f;
  if (mode == 3) gate = 1.f/(1.f + expf(-(*skip_gate)));
#pragma unroll
  for (int i = 0; i < 4; i++){
#pragma unroll
    for (int j = 0; j < 4; j++){
#pragma unroll
      for (int r = 0; r < 4; r++){
        int gr = row0 + R + 16*i + quad*4 + r;
        int gc = col0 + Cb + 16*j + l16;
        if (gr >= M || gc >= N) continue;
        float v = acc[i][j][r] + (bias ? bias[gc] : 0.f);
        if (mode == 1) v = fmaxf(v, 0.f);
        else if (mode == 2) v *= pvec[gc >> 7] * 0.08838834764831845f;
        else if (mode == 3) v = gate*v + (1.f - gate)*(float)skipx[(long long)gr*HID + gc];
        if (mode == 4) ((float*)Cout)[(long long)gr*ldc + gc] = 1.f/(1.f + expf(-v));
        else ((bf16_t*)Cout)[(long long)gr*ldc + gc] = (bf16_t)v;
      }
    }
  }
}

// ---------------- fused weight transpose+cast: W[K,N](lda) fp32 -> Wt[N,K] bf16 ----------------
struct TW { const float* W; bf16_t* out; int lda; int K; int N; };

__global__ __launch_bounds__(256) void prep_weights_k(TW w0, TW w1, TW w2, TW w3, TW w4){
  TW tw;
  switch (blockIdx.z){
    case 0: tw = w0; break; case 1: tw = w1; break; case 2: tw = w2; break;
    case 3: tw = w3; break; default: tw = w4; break;
  }
  __shared__ float tile[32][33];
  int bx = blockIdx.x*32, by = blockIdx.y*32;
  if (by >= tw.K || bx >= tw.N) return;
  int tx = threadIdx.x, ty = threadIdx.y;
  for (int i = 0; i < 32; i += 8){
    int k = by + ty + i, n = bx + tx;
    tile[ty+i][tx] = (k < tw.K && n < tw.N) ? tw.W[(long long)k*tw.lda + n] : 0.f;
  }
  __syncthreads();
  for (int i = 0; i < 32; i += 8){
    int n = bx + ty + i, k = by + tx;
    if (n < tw.N && k < tw.K) tw.out[(long long)n*tw.K + k] = (bf16_t)tile[tx][ty+i];
  }
}

// ---------------- fold Wk_rel/Wv_rel into kqv_p weights, output transposed bf16 ----------------
// Wkvt[n'][m] = sum_k Wkqv_p[m, off + k] * rel[h, k, n],  n' = kv*256 + h*128 + n, off = kv*512 + h*128
// bkv[n'] = sum_k bkqv_p[off + k] * rel[h, k, n]
__global__ __launch_bounds__(256) void prep_fold_k(
    const float* __restrict__ Wkqv_p, const float* __restrict__ bkqv_p,
    const float* __restrict__ Wk_rel, const float* __restrict__ Wv_rel,
    bf16_t* __restrict__ Wkvt, float* __restrict__ bkv)
{
  int np = blockIdx.x;            // 0..511
  int kv = np >> 8, h = (np >> 7) & 1, n = np & 127;
  int off = kv*512 + h*128;
  const float* rel = (kv ? Wv_rel : Wk_rel) + h*128*128 + n;  // column n, stride 128
  __shared__ float relcol[128];
  int t = threadIdx.x;
  if (t < 128) relcol[t] = rel[t*128];
  __syncthreads();
  int m = t;                      // 0..255
  const float* wp = Wkqv_p + (long long)m*768 + off;
  float acc = 0.f;
#pragma unroll 8
  for (int k = 0; k < 128; k++) acc += wp[k] * relcol[k];
  Wkvt[(long long)np*256 + m] = (bf16_t)acc;
  if (t == 0){
    float b = 0.f;
    for (int k = 0; k < 128; k++) b += bkqv_p[off + k] * relcol[k];
    bkv[np] = b;
  }
}

// ---------------- CSR build ----------------
__global__ void hist_k(const int* __restrict__ dst, int E, int* __restrict__ deg){
  int i = blockIdx.x*256 + threadIdx.x;
  if (i < E) atomicAdd(&deg[dst[i]], 1);
}

__global__ __launch_bounds__(256) void partial_sum_k(
    const int* __restrict__ deg, int n, int* __restrict__ part)
{
  __shared__ int sdata[4];
  int i = blockIdx.x*256 + threadIdx.x;
  int v = (i < n) ? deg[i] : 0;
#pragma unroll
  for (int o = 32; o; o >>= 1) v += __shfl_xor(v, o);
  int lane = threadIdx.x & 63, wid = threadIdx.x >> 6;
  if (lane == 0) sdata[wid] = v;
  __syncthreads();
  if (threadIdx.x == 0) part[blockIdx.x] = sdata[0]+sdata[1]+sdata[2]+sdata[3];
}

__global__ __launch_bounds__(256) void scan_part_k(
    int* __restrict__ part, int nb, int* __restrict__ total_out)
{
  __shared__ int ws[4]; __shared__ int tot;
  int t = threadIdx.x;
  int v = (t < nb) ? part[t] : 0;
  int lane = t & 63, wid = t >> 6;
  int x = v;
#pragma unroll
  for (int o = 1; o < 64; o <<= 1){ int y = __shfl_up(x, o); if (lane >= o) x += y; }
  if (lane == 63) ws[wid] = x;
  __syncthreads();
  if (t == 0){ int s = 0; for (int i = 0; i < 4; i++){ int tmp = ws[i]; ws[i] = s; s += tmp; } tot = s; }
  __syncthreads();
  int excl = x - v + ws[wid];
  if (t < nb) part[t] = excl;
  if (t == 0) *total_out = tot;
}

__global__ __launch_bounds__(256) void scan_offs_k(
    const int* __restrict__ deg, int n, const int* __restrict__ part,
    int* __restrict__ offs, int* __restrict__ cursor)
{
  __shared__ int ws[4];
  int t = threadIdx.x;
  int i = blockIdx.x*256 + t;
  int v = (i < n) ? deg[i] : 0;
  int lane = t & 63, wid = t >> 6;
  int x = v;
#pragma unroll
  for (int o = 1; o < 64; o <<= 1){ int y = __shfl_up(x, o); if (lane >= o) x += y; }
  if (lane == 63) ws[wid] = x;
  __syncthreads();
  int pre = 0;
  for (int k = 0; k < wid; k++) pre += ws[k];
  if (i < n){ int o = part[blockIdx.x] + x - v + pre; offs[i] = o; cursor[i] = o; }
}

__global__ void scatter_k(const int* __restrict__ src, const int* __restrict__ dst, int E,
                          int* __restrict__ cursor, int* __restrict__ esrc){
  int i = blockIdx.x*256 + threadIdx.x;
  if (i < E){
    int s = src[i], d = dst[i];
    int p = atomicAdd(&cursor[d], 1);
    esrc[p] = s;
  }
}

// ---------------- fused attention: one wave per dst, 8 edges per batch ----------------
// (At its structural plateau: ~114 us, HBM 46%, three restructures flat. Unchanged this round.)
__global__ __launch_bounds__(256) void attn_fused_k(
    const bf16_t* __restrict__ q, const bf16_t* __restrict__ keve,
    const int* __restrict__ offs, const int* __restrict__ esrc,
    int Na, bf16_t* __restrict__ agg)
{
  int gid = blockIdx.x*256 + threadIdx.x;
  int dst = gid >> 6, lane = gid & 63;
  if (dst >= Na) return;
  const int hl = lane & 31;       // position within half-wave
  const int half = lane >> 5;     // which member of the edge pair
  bf16x8 qv = *(const bf16x8*)(q + (size_t)dst*256 + hl*8);
  float qf[8];
#pragma unroll
  for (int j = 0; j < 8; j++) qf[j] = (float)qv[j];
  int beg = offs[dst], end = offs[dst+1];
  int cnt = end - beg;
  int cap = cnt < 64 ? cnt : 64;
  int myidx = 0;
  if (cnt > 0) myidx = esrc[beg + (lane < cnt ? lane : cnt - 1)];   // coalesced preload
  float n[8] = {};
  float den = 0.f;

  int npairs = cap >> 1;
  int it = 0;
  for (; it + 4 <= npairs; it += 4){
    int es0 = __shfl(myidx, 2*it     + half);
    int es1 = __shfl(myidx, 2*it + 2 + half);
    int es2 = __shfl(myidx, 2*it + 4 + half);
    int es3 = __shfl(myidx, 2*it + 6 + half);
    const bf16_t* r0 = keve + ((size_t)(unsigned)es0 << 9);
    const bf16_t* r1 = keve + ((size_t)(unsigned)es1 << 9);
    const bf16_t* r2 = keve + ((size_t)(unsigned)es2 << 9);
    const bf16_t* r3 = keve + ((size_t)(unsigned)es3 << 9);
    bf16x8 k0 = *(const bf16x8*)(r0 + hl*8);
    bf16x8 k1 = *(const bf16x8*)(r1 + hl*8);
    bf16x8 k2 = *(const bf16x8*)(r2 + hl*8);
    bf16x8 k3 = *(const bf16x8*)(r3 + hl*8);
    bf16x8 v0 = *(const bf16x8*)(r0 + 256 + hl*8);
    bf16x8 v1 = *(const bf16x8*)(r1 + 256 + hl*8);
    bf16x8 v2 = *(const bf16x8*)(r2 + 256 + hl*8);
    bf16x8 v3 = *(const bf16x8*)(r3 + 256 + hl*8);
    float p0 = 0.f, p1 = 0.f, p2 = 0.f, p3 = 0.f;
#pragma unroll
    for (int j = 0; j < 8; j++){
      p0 += qf[j]*(float)k0[j];
      p1 += qf[j]*(float)k1[j];
      p2 += qf[j]*(float)k2[j];
      p3 += qf[j]*(float)k3[j];
    }
#pragma unroll
    for (int o = 1; o <= 8; o <<= 1){        // 4 interleaved reduce chains
      p0 += __shfl_xor(p0, o);
      p1 += __shfl_xor(p1, o);
      p2 += __shfl_xor(p2, o);
      p3 += __shfl_xor(p3, o);
    }
    float w0 = __expf(p0), w1 = __expf(p1), w2 = __expf(p2), w3 = __expf(p3);
#pragma unroll
    for (int j = 0; j < 8; j++)
      n[j] += w0*(float)v0[j] + w1*(float)v1[j] + w2*(float)v2[j] + w3*(float)v3[j];
    den += w0 + w1 + w2 + w3;
  }
  for (; it < npairs; ++it){       // remainder pairs (0-3)
    int es = __shfl(myidx, 2*it + half);
    const bf16_t* row = keve + ((size_t)(unsigned)es << 9);
    bf16x8 kv = *(const bf16x8*)(row + hl*8);
    bf16x8 vv = *(const bf16x8*)(row + 256 + hl*8);
    float p = qf[0]*(float)kv[0] + qf[1]*(float)kv[1]
            + qf[2]*(float)kv[2] + qf[3]*(float)kv[3]
            + qf[4]*(float)kv[4] + qf[5]*(float)kv[5]
            + qf[6]*(float)kv[6] + qf[7]*(float)kv[7];
    p += __shfl_xor(p, 1); p += __shfl_xor(p, 2);
    p += __shfl_xor(p, 4); p += __shfl_xor(p, 8);
    float wgt = __expf(p);
#pragma unroll
    for (int j = 0; j < 8; j++) n[j] += wgt*(float)vv[j];
    den += wgt;
  }
  if (cap & 1){                   // odd leftover within the register window
    int es = __shfl(myidx, cap - 1);
    const bf16_t* row = keve + ((size_t)(unsigned)es << 9);
    bf16x8 kv = *(const bf16x8*)(row + hl*8);
    bf16x8 vv = *(const bf16x8*)(row + 256 + hl*8);
    float p = qf[0]*(float)kv[0] + qf[1]*(float)kv[1]
            + qf[2]*(float)kv[2] + qf[3]*(float)kv[3]
            + qf[4]*(float)kv[4] + qf[5]*(float)kv[5]
            + qf[6]*(float)kv[6] + qf[7]*(float)kv[7];
    p += __shfl_xor(p, 1); p += __shfl_xor(p, 2);
    p += __shfl_xor(p, 4); p += __shfl_xor(p, 8);
    float wgt = (half == 0) ? __expf(p) : 0.f;      // only half 0 owns this edge
#pragma unroll
    for (int j = 0; j < 8; j++) n[j] += wgt*(float)vv[j];
    den += wgt;
  }
  // ultra-rare tail: degree > 64 (Binomial(800k,1/50k) makes this ~impossible, but be correct)
  for (int i = beg + 64; i < end; i += 2){
    int e2 = i + half;
    int es = esrc[(e2 < end) ? e2 : i];
    const bf16_t* row = keve + ((size_t)(unsigned)es << 9);
    bf16x8 kv = *(const bf16x8*)(row + hl*8);
    bf16x8 vv = *(const bf16x8*)(row + 256 + hl*8);
    float p = qf[0]*(float)kv[0] + qf[1]*(float)kv[1]
            + qf[2]*(float)kv[2] + qf[3]*(float)kv[3]
            + qf[4]*(float)kv[4] + qf[5]*(float)kv[5]
            + qf[6]*(float)kv[6] + qf[7]*(float)kv[7];
    p += __shfl_xor(p, 1); p += __shfl_xor(p, 2);
    p += __shfl_xor(p, 4); p += __shfl_xor(p, 8);
    float wgt = (e2 < end) ? __expf(p) : 0.f;
#pragma unroll
    for (int j = 0; j < 8; j++) n[j] += wgt*(float)vv[j];
    den += wgt;
  }
  // merge the two half-wave edge streams (lane l and l+32 hold identical components)
  den += __shfl_xor(den, 32);
#pragma unroll
  for (int j = 0; j < 8; j++) n[j] += __shfl_xor(n[j], 32);
  if (half == 0){
    float r = 1.f/(den + 1e-16f);
    bf16x8 o;
#pragma unroll
    for (int j = 0; j < 8; j++) o[j] = (bf16_t)(n[j]*r);
    *(bf16x8*)(agg + (size_t)dst*256 + hl*8) = o;
  }
}

extern "C" void kernel_launch(void* const* d_in, const int* in_sizes, int n_in,
                              void* d_out, int out_size, void* d_ws, size_t ws_size,
                              hipStream_t stream)
{
  (void)n_in; (void)out_size; (void)ws_size;
  const float* x_author    = (const float*)d_in[0];
  const float* x_paper     = (const float*)d_in[1];
  const int*   eb_src      = (const int*)d_in[4];
  const int*   eb_dst      = (const int*)d_in[5];
  const int*   input_nodes = (const int*)d_in[6];
  const float* W_in_a  = (const float*)d_in[7];
  const float* b_in_a  = (const float*)d_in[8];
  const float* W_in_p  = (const float*)d_in[9];
  const float* b_in_p  = (const float*)d_in[10];
  const float* Wkqv_a  = (const float*)d_in[11];
  const float* bkqv_a  = (const float*)d_in[12];
  const float* Wkqv_p  = (const float*)d_in[13];
  const float* bkqv_p  = (const float*)d_in[14];
  const float* Wk_rel_b= (const float*)d_in[17];
  const float* Wv_rel_b= (const float*)d_in[18];
  const float* p_b     = (const float*)d_in[20];
  const float* Wout_a  = (const float*)d_in[21];
  const float* bout_a  = (const float*)d_in[22];
  const float* skip_a  = (const float*)d_in[25];
  const float* W_dec   = (const float*)d_in[27];
  const float* b_dec   = (const float*)d_in[28];

  const int Na = in_sizes[0] / 128;
  const int Np = in_sizes[1] / 128;
  const int E  = in_sizes[4];
  const int NI = in_sizes[6];

  char* w = (char*)d_ws;
  auto alloc = [&](size_t bytes)->void*{
    void* p = (void*)w; w += (bytes + 255) & ~(size_t)255; return p;
  };
  bf16_t* xa_bf = (bf16_t*)alloc((size_t)Na*HID*2);
  bf16_t* xp_bf = (bf16_t*)alloc((size_t)Np*HID*2);
  bf16_t* qb    = (bf16_t*)alloc((size_t)Na*HID*2);  // reused as za after attention
  bf16_t* aggb  = (bf16_t*)alloc((size_t)Na*HID*2);
  bf16_t* zin   = (bf16_t*)alloc((size_t)NI*HID*2);
  bf16_t* Wt_in_a = (bf16_t*)alloc(128*HID*2);
  bf16_t* Wt_in_p = (bf16_t*)alloc(128*HID*2);
  bf16_t* Wt_q    = (bf16_t*)alloc(HID*HID*2);
  bf16_t* Wt_out  = (bf16_t*)alloc(HID*HID*2);
  bf16_t* Wt_dec  = (bf16_t*)alloc(HID*HID*2);
  bf16_t* Wkvt    = (bf16_t*)alloc((size_t)512*HID*2);
  float*  bkv     = (float*)alloc(512*4);
  int* deg    = (int*)alloc((size_t)Na*4);
  int* offs   = (int*)alloc((size_t)(Na+1)*4);
  int* cursor = (int*)alloc((size_t)Na*4);
  int* part   = (int*)alloc(1024);
  int* esrc   = (int*)alloc((size_t)E*4);

  // keve [Np,512] bf16 (ke||ve interleaved per row) lives in d_out (51.2 of 102.4 MB),
  // dead before the final GEMM overwrites d_out.
  bf16_t* keve = (bf16_t*)d_out;
  bf16_t* zab  = qb;

  dim3 blk(256);

  // fused weight transposes (fp32 -> bf16, K-major)
  TW tw0 = { W_in_a,       Wt_in_a, 256, 128, 256 };
  TW tw1 = { W_in_p,       Wt_in_p, 256, 128, 256 };
  TW tw2 = { Wkqv_a + 256, Wt_q,    768, 256, 256 };
  TW tw3 = { Wout_a,       Wt_out,  256, 256, 256 };
  TW tw4 = { W_dec,        Wt_dec,  256, 256, 256 };
  prep_weights_k<<<dim3(8,8,5), dim3(32,8), 0, stream>>>(tw0, tw1, tw2, tw3, tw4);
  // fold rel-matrices into kqv_p (transposed bf16 out) + folded bias
  prep_fold_k<<<512, blk, 0, stream>>>(Wkqv_p, bkqv_p, Wk_rel_b, Wv_rel_b, Wkvt, bkv);

  dim3 gNa(2, (Na+127)/128);
  dim3 gNp(2, (Np+127)/128);
  // xa = relu(x_author @ W_in_a + b)   (fp32 A reg-staged)
  mfma_gemm_k<<<gNa, blk, 0, stream>>>(x_author, 128, Wt_in_a, 128, b_in_a, xa_bf, HID,
      Na, 256, 128, 1, 0, 1, nullptr, nullptr, nullptr, nullptr);
  // xp = relu(x_paper @ W_in_p + b)
  mfma_gemm_k<<<gNp, blk, 0, stream>>>(x_paper, 128, Wt_in_p, 128, b_in_p, xp_bf, HID,
      Np, 256, 128, 1, 0, 1, nullptr, nullptr, nullptr, nullptr);
  // q = (xa @ Wq + b) * p_b[h]/sqrt(128)   (A via global_load_lds)
  mfma_gemm_k<<<gNa, blk, 0, stream>>>(xa_bf, HID, Wt_q, HID, bkqv_a + 256, qb, HID,
      Na, 256, 256, 2, 0, 0, nullptr, p_b, nullptr, nullptr);
  // keve = xp @ [Wk_fold || Wv_fold] + [bk||bv]   (N=512, interleaved rows)
  mfma_gemm_k<<<dim3(4,(Np+127)/128), blk, 0, stream>>>(xp_bf, HID, Wkvt, HID, bkv, keve, 512,
      Np, 512, 256, 0, 0, 0, nullptr, nullptr, nullptr, nullptr);
  // CSR over edge_b (dst = authors)
  hipMemsetAsync(deg, 0, (size_t)Na*4, stream);
  hist_k<<<(E+255)/256, blk, 0, stream>>>(eb_dst, E, deg);
  int nb = (Na+255)/256;
  partial_sum_k<<<nb, blk, 0, stream>>>(deg, Na, part);
  scan_part_k<<<1, blk, 0, stream>>>(part, nb, offs+Na);
  scan_offs_k<<<nb, blk, 0, stream>>>(deg, Na, part, offs, cursor);
  scatter_k<<<(E+255)/256, blk, 0, stream>>>(eb_src, eb_dst, E, cursor, esrc);
  // fused attention: logits + softmax + weighted aggregation, 8 edges per batch
  attn_fused_k<<<(Na+3)/4, blk, 0, stream>>>(qb, keve, offs, esrc, Na, aggb);
  // za = g*(gelu(agg)@Wout + b) + (1-g)*xa   (gelu A reg-staged; za reuses q buffer)
  mfma_gemm_k<<<gNa, blk, 0, stream>>>(aggb, HID, Wt_out, HID, bout_a, zab, HID,
      Na, 256, 256, 3, 1, 0, nullptr, nullptr, xa_bf, skip_a);
  // zin = za[input_nodes] @ W_dec + b   (gathered A via per-lane gload src)
  mfma_gemm_k<<<dim3(2,(NI+127)/128), blk, 0, stream>>>(zab, HID, Wt_dec, HID, b_dec, zin, HID,
      NI, 256, 256, 0, 0, 0, input_nodes, nullptr, nullptr, nullptr);
  // out = sigmoid(zin @ za^T)  (fp32 out)
  mfma_gemm_k<<<dim3((Na+127)/128, (NI+127)/128), blk, 0, stream>>>(zin, HID, zab, HID, nullptr,
      (float*)d_out, Na, NI, Na, 256, 4, 0, 0, nullptr, nullptr, nullptr, nullptr);
}

// Round 8
// 701.559 us; speedup vs baseline: 1.1813x; 1.0869x over previous
//
#include <hip/hip_runtime.h>
#include <math.h>

#define HID 256

typedef __bf16 bf16_t;
typedef __attribute__((ext_vector_type(8))) __bf16 bf16x8;
typedef __attribute__((ext_vector_type(4))) __bf16 bf16x4;
typedef __attribute__((ext_vector_type(4))) float f32x4;

__device__ __forceinline__ float gelu_f(float x){
  return 0.5f * x * (1.0f + erff(x * 0.70710678118654752440f));
}

// async global->LDS 16B: linear LDS dest (base + lane*16), per-lane global src
__device__ __forceinline__ void gload16(const void* g, void* l){
  __builtin_amdgcn_global_load_lds(
      (const __attribute__((address_space(1))) unsigned int*)g,
      (__attribute__((address_space(3))) unsigned int*)l, 16, 0, 0);
}

// ---------------- bf16 MFMA NT GEMM body: C = epi(A[M,K] @ Bt[N,K]^T + bias) ----------------
// mode: 0 plain->bf16, 1 relu->bf16, 2 qscale->bf16, 3 skipblend->bf16, 4 sigmoid->f32
// LDS: linear [128][64] per operand, XOR-swizzled 16B chunks (chunk p ^ (row&7)), rule #21:
// gload_lds path pre-swizzles the per-lane SOURCE address; reg-staged paths swizzle the WRITE;
// reads apply the same XOR. (verified round 7: bit-identical output, -63 us)
struct GArgs {
  const void* A; int lda;
  const bf16_t* Bt; int ldb;
  const float* bias;
  void* Cout; int ldc;
  int M, N, K;
  int mode, a_gelu, a_f32;
  const int* a_rows;
  const float* pvec;
  const bf16_t* skipx;
  const float* skip_gate;
};

__device__ void gemm_body(const GArgs& g){
  __shared__ bf16_t As[128*64];
  __shared__ bf16_t Bs[128*64];
  const int row0 = blockIdx.y*128, col0 = blockIdx.x*128;
  if (row0 >= g.M || col0 >= g.N) return;      // block-uniform early exit (empty z-slices)
  const int t = threadIdx.x;
  const int wave = t >> 6, lane = t & 63;
  const int quad = lane >> 4, l16 = lane & 15;
  const int R = (wave>>1)*64, Cb = (wave&1)*64;
  const int lrow = lane >> 3;           // row within 8-row group (0..7)
  const int schunk = (lane & 7) ^ lrow; // pre-swizzled source 16B-chunk index
  const bool a_direct = (!g.a_f32 && !g.a_gelu);
  f32x4 acc[4][4] = {};

  for (int k0 = 0; k0 < g.K; k0 += 64){
    // ---- stage A ----
    if (a_direct){
#pragma unroll
      for (int i = 0; i < 4; i++){
        int r0 = wave*32 + i*8;
        int gr = row0 + r0 + lrow;
        int rr = gr < g.M ? gr : g.M-1;        // clamp: finite garbage -> masked rows only
        int ar = g.a_rows ? g.a_rows[rr] : rr;
        gload16((const bf16_t*)g.A + (long long)ar*g.lda + k0 + schunk*8, As + r0*64);
      }
    } else {
#pragma unroll
      for (int i = 0; i < 4; i++){
        int id = t + i*256;
        int r = id >> 3, c4 = id & 7;
        int gr = row0 + r;
        bf16x8 v = {};
        if (gr < g.M){
          if (g.a_f32){
            const float* p = (const float*)g.A + (long long)gr*g.lda + k0 + c4*8;
            float4 f0 = *(const float4*)p;
            float4 f1 = *(const float4*)(p + 4);
            v[0]=(bf16_t)f0.x; v[1]=(bf16_t)f0.y; v[2]=(bf16_t)f0.z; v[3]=(bf16_t)f0.w;
            v[4]=(bf16_t)f1.x; v[5]=(bf16_t)f1.y; v[6]=(bf16_t)f1.z; v[7]=(bf16_t)f1.w;
          } else {
            v = *(const bf16x8*)((const bf16_t*)g.A + (long long)gr*g.lda + k0 + c4*8);
#pragma unroll
            for (int j = 0; j < 8; j++) v[j] = (bf16_t)gelu_f((float)v[j]);
          }
        }
        *(bf16x8*)(As + r*64 + ((c4 ^ (r&7))*8)) = v;   // write-side swizzle
      }
    }
    // ---- stage B (always bf16) ----
#pragma unroll
    for (int i = 0; i < 4; i++){
      int r0 = wave*32 + i*8;
      int gc = col0 + r0 + lrow;
      int rc = gc < g.N ? gc : g.N-1;
      gload16(g.Bt + (long long)rc*g.ldb + k0 + schunk*8, Bs + r0*64);
    }
    __syncthreads();
#pragma unroll
    for (int kk = 0; kk < 64; kk += 32){
      const int cb = quad + (kk >> 3);   // logical 16B chunk for this fragment
      bf16x8 af[4], bfr[4];
#pragma unroll
      for (int i = 0; i < 4; i++){
        int row = R + 16*i + l16;
        af[i]  = *(const bf16x8*)(As + row*64 + ((cb ^ (row&7))*8));
      }
#pragma unroll
      for (int j = 0; j < 4; j++){
        int row = Cb + 16*j + l16;
        bfr[j] = *(const bf16x8*)(Bs + row*64 + ((cb ^ (row&7))*8));
      }
#pragma unroll
      for (int i = 0; i < 4; i++)
#pragma unroll
        for (int j = 0; j < 4; j++)
          acc[i][j] = __builtin_amdgcn_mfma_f32_16x16x32_bf16(af[i], bfr[j], acc[i][j], 0, 0, 0);
    }
    __syncthreads();
  }

  float gate = 0.f;
  if (g.mode == 3) gate = 1.f/(1.f + expf(-(*g.skip_gate)));
#pragma unroll
  for (int i = 0; i < 4; i++){
#pragma unroll
    for (int j = 0; j < 4; j++){
#pragma unroll
      for (int r = 0; r < 4; r++){
        int gr = row0 + R + 16*i + quad*4 + r;
        int gc = col0 + Cb + 16*j + l16;
        if (gr >= g.M || gc >= g.N) continue;
        float v = acc[i][j][r] + (g.bias ? g.bias[gc] : 0.f);
        if (g.mode == 1) v = fmaxf(v, 0.f);
        else if (g.mode == 2) v *= g.pvec[gc >> 7] * 0.08838834764831845f;
        else if (g.mode == 3) v = gate*v + (1.f - gate)*(float)g.skipx[(long long)gr*HID + gc];
        if (g.mode == 4) ((float*)g.Cout)[(long long)gr*g.ldc + gc] = 1.f/(1.f + expf(-v));
        else ((bf16_t*)g.Cout)[(long long)gr*g.ldc + gc] = (bf16_t)v;
      }
    }
  }
}

// batched launch: z=0 -> g0 GEMM, z=1 -> g1 GEMM, z=2 -> grid-stride edge op
// eop 1: hist  (atomicAdd deg[e_a[i]])   eop 2: scatter (esrc[cursor[e_b[i]]++] = e_a[i])
__global__ __launch_bounds__(256) void gemm_batch_k(
    GArgs g0, GArgs g1, int eop,
    const int* __restrict__ e_a, const int* __restrict__ e_b, int E,
    int* __restrict__ e_c, int* __restrict__ e_d)
{
  if (blockIdx.z == 2){
    int nblk = gridDim.x*gridDim.y;
    int bid  = blockIdx.y*gridDim.x + blockIdx.x;
    for (int i = bid*256 + threadIdx.x; i < E; i += nblk*256){
      if (eop == 1) atomicAdd(&e_c[e_a[i]], 1);
      else { int s = e_a[i], d = e_b[i]; int p = atomicAdd(&e_c[d], 1); e_d[p] = s; }
    }
    return;
  }
  gemm_body(blockIdx.z ? g1 : g0);
}

// ---------------- fused weight transpose+cast: W[K,N](lda) fp32 -> Wt[N,K] bf16 ----------------
struct TW { const float* W; bf16_t* out; int lda; int K; int N; };

__global__ __launch_bounds__(256) void prep_weights_k(TW w0, TW w1, TW w2, TW w3, TW w4){
  TW tw;
  switch (blockIdx.z){
    case 0: tw = w0; break; case 1: tw = w1; break; case 2: tw = w2; break;
    case 3: tw = w3; break; default: tw = w4; break;
  }
  __shared__ float tile[32][33];
  int bx = blockIdx.x*32, by = blockIdx.y*32;
  if (by >= tw.K || bx >= tw.N) return;
  int tx = threadIdx.x, ty = threadIdx.y;
  for (int i = 0; i < 32; i += 8){
    int k = by + ty + i, n = bx + tx;
    tile[ty+i][tx] = (k < tw.K && n < tw.N) ? tw.W[(long long)k*tw.lda + n] : 0.f;
  }
  __syncthreads();
  for (int i = 0; i < 32; i += 8){
    int n = bx + ty + i, k = by + tx;
    if (n < tw.N && k < tw.K) tw.out[(long long)n*tw.K + k] = (bf16_t)tile[tx][ty+i];
  }
}

// ---------------- fold Wk_rel/Wv_rel into kqv_p weights, output transposed bf16 ----------------
__global__ __launch_bounds__(256) void prep_fold_k(
    const float* __restrict__ Wkqv_p, const float* __restrict__ bkqv_p,
    const float* __restrict__ Wk_rel, const float* __restrict__ Wv_rel,
    bf16_t* __restrict__ Wkvt, float* __restrict__ bkv)
{
  int np = blockIdx.x;            // 0..511
  int kv = np >> 8, h = (np >> 7) & 1, n = np & 127;
  int off = kv*512 + h*128;
  const float* rel = (kv ? Wv_rel : Wk_rel) + h*128*128 + n;  // column n, stride 128
  __shared__ float relcol[128];
  int t = threadIdx.x;
  if (t < 128) relcol[t] = rel[t*128];
  __syncthreads();
  int m = t;                      // 0..255
  const float* wp = Wkqv_p + (long long)m*768 + off;
  float acc = 0.f;
#pragma unroll 8
  for (int k = 0; k < 128; k++) acc += wp[k] * relcol[k];
  Wkvt[(long long)np*256 + m] = (bf16_t)acc;
  if (t == 0){
    float b = 0.f;
    for (int k = 0; k < 128; k++) b += bkqv_p[off + k] * relcol[k];
    bkv[np] = b;
  }
}

// ---------------- CSR scan kernels ----------------
__global__ __launch_bounds__(256) void partial_sum_k(
    const int* __restrict__ deg, int n, int* __restrict__ part)
{
  __shared__ int sdata[4];
  int i = blockIdx.x*256 + threadIdx.x;
  int v = (i < n) ? deg[i] : 0;
#pragma unroll
  for (int o = 32; o; o >>= 1) v += __shfl_xor(v, o);
  int lane = threadIdx.x & 63, wid = threadIdx.x >> 6;
  if (lane == 0) sdata[wid] = v;
  __syncthreads();
  if (threadIdx.x == 0) part[blockIdx.x] = sdata[0]+sdata[1]+sdata[2]+sdata[3];
}

__global__ __launch_bounds__(256) void scan_part_k(
    int* __restrict__ part, int nb, int* __restrict__ total_out)
{
  __shared__ int ws[4]; __shared__ int tot;
  int t = threadIdx.x;
  int v = (t < nb) ? part[t] : 0;
  int lane = t & 63, wid = t >> 6;
  int x = v;
#pragma unroll
  for (int o = 1; o < 64; o <<= 1){ int y = __shfl_up(x, o); if (lane >= o) x += y; }
  if (lane == 63) ws[wid] = x;
  __syncthreads();
  if (t == 0){ int s = 0; for (int i = 0; i < 4; i++){ int tmp = ws[i]; ws[i] = s; s += tmp; } tot = s; }
  __syncthreads();
  int excl = x - v + ws[wid];
  if (t < nb) part[t] = excl;
  if (t == 0) *total_out = tot;
}

__global__ __launch_bounds__(256) void scan_offs_k(
    const int* __restrict__ deg, int n, const int* __restrict__ part,
    int* __restrict__ offs, int* __restrict__ cursor)
{
  __shared__ int ws[4];
  int t = threadIdx.x;
  int i = blockIdx.x*256 + t;
  int v = (i < n) ? deg[i] : 0;
  int lane = t & 63, wid = t >> 6;
  int x = v;
#pragma unroll
  for (int o = 1; o < 64; o <<= 1){ int y = __shfl_up(x, o); if (lane >= o) x += y; }
  if (lane == 63) ws[wid] = x;
  __syncthreads();
  int pre = 0;
  for (int k = 0; k < wid; k++) pre += ws[k];
  if (i < n){ int o = part[blockIdx.x] + x - v + pre; offs[i] = o; cursor[i] = o; }
}

// ---------------- fused attention: one wave per dst, 8 edges per batch ----------------
// (At its structural plateau: ~114 us, HBM 46%, three restructures flat. Unchanged.)
__global__ __launch_bounds__(256) void attn_fused_k(
    const bf16_t* __restrict__ q, const bf16_t* __restrict__ keve,
    const int* __restrict__ offs, const int* __restrict__ esrc,
    int Na, bf16_t* __restrict__ agg)
{
  int gid = blockIdx.x*256 + threadIdx.x;
  int dst = gid >> 6, lane = gid & 63;
  if (dst >= Na) return;
  const int hl = lane & 31;       // position within half-wave
  const int half = lane >> 5;     // which member of the edge pair
  bf16x8 qv = *(const bf16x8*)(q + (size_t)dst*256 + hl*8);
  float qf[8];
#pragma unroll
  for (int j = 0; j < 8; j++) qf[j] = (float)qv[j];
  int beg = offs[dst], end = offs[dst+1];
  int cnt = end - beg;
  int cap = cnt < 64 ? cnt : 64;
  int myidx = 0;
  if (cnt > 0) myidx = esrc[beg + (lane < cnt ? lane : cnt - 1)];   // coalesced preload
  float n[8] = {};
  float den = 0.f;

  int npairs = cap >> 1;
  int it = 0;
  for (; it + 4 <= npairs; it += 4){
    int es0 = __shfl(myidx, 2*it     + half);
    int es1 = __shfl(myidx, 2*it + 2 + half);
    int es2 = __shfl(myidx, 2*it + 4 + half);
    int es3 = __shfl(myidx, 2*it + 6 + half);
    const bf16_t* r0 = keve + ((size_t)(unsigned)es0 << 9);
    const bf16_t* r1 = keve + ((size_t)(unsigned)es1 << 9);
    const bf16_t* r2 = keve + ((size_t)(unsigned)es2 << 9);
    const bf16_t* r3 = keve + ((size_t)(unsigned)es3 << 9);
    bf16x8 k0 = *(const bf16x8*)(r0 + hl*8);
    bf16x8 k1 = *(const bf16x8*)(r1 + hl*8);
    bf16x8 k2 = *(const bf16x8*)(r2 + hl*8);
    bf16x8 k3 = *(const bf16x8*)(r3 + hl*8);
    bf16x8 v0 = *(const bf16x8*)(r0 + 256 + hl*8);
    bf16x8 v1 = *(const bf16x8*)(r1 + 256 + hl*8);
    bf16x8 v2 = *(const bf16x8*)(r2 + 256 + hl*8);
    bf16x8 v3 = *(const bf16x8*)(r3 + 256 + hl*8);
    float p0 = 0.f, p1 = 0.f, p2 = 0.f, p3 = 0.f;
#pragma unroll
    for (int j = 0; j < 8; j++){
      p0 += qf[j]*(float)k0[j];
      p1 += qf[j]*(float)k1[j];
      p2 += qf[j]*(float)k2[j];
      p3 += qf[j]*(float)k3[j];
    }
#pragma unroll
    for (int o = 1; o <= 8; o <<= 1){        // 4 interleaved reduce chains
      p0 += __shfl_xor(p0, o);
      p1 += __shfl_xor(p1, o);
      p2 += __shfl_xor(p2, o);
      p3 += __shfl_xor(p3, o);
    }
    float w0 = __expf(p0), w1 = __expf(p1), w2 = __expf(p2), w3 = __expf(p3);
#pragma unroll
    for (int j = 0; j < 8; j++)
      n[j] += w0*(float)v0[j] + w1*(float)v1[j] + w2*(float)v2[j] + w3*(float)v3[j];
    den += w0 + w1 + w2 + w3;
  }
  for (; it < npairs; ++it){       // remainder pairs (0-3)
    int es = __shfl(myidx, 2*it + half);
    const bf16_t* row = keve + ((size_t)(unsigned)es << 9);
    bf16x8 kv = *(const bf16x8*)(row + hl*8);
    bf16x8 vv = *(const bf16x8*)(row + 256 + hl*8);
    float p = qf[0]*(float)kv[0] + qf[1]*(float)kv[1]
            + qf[2]*(float)kv[2] + qf[3]*(float)kv[3]
            + qf[4]*(float)kv[4] + qf[5]*(float)kv[5]
            + qf[6]*(float)kv[6] + qf[7]*(float)kv[7];
    p += __shfl_xor(p, 1); p += __shfl_xor(p, 2);
    p += __shfl_xor(p, 4); p += __shfl_xor(p, 8);
    float wgt = __expf(p);
#pragma unroll
    for (int j = 0; j < 8; j++) n[j] += wgt*(float)vv[j];
    den += wgt;
  }
  if (cap & 1){                   // odd leftover within the register window
    int es = __shfl(myidx, cap - 1);
    const bf16_t* row = keve + ((size_t)(unsigned)es << 9);
    bf16x8 kv = *(const bf16x8*)(row + hl*8);
    bf16x8 vv = *(const bf16x8*)(row + 256 + hl*8);
    float p = qf[0]*(float)kv[0] + qf[1]*(float)kv[1]
            + qf[2]*(float)kv[2] + qf[3]*(float)kv[3]
            + qf[4]*(float)kv[4] + qf[5]*(float)kv[5]
            + qf[6]*(float)kv[6] + qf[7]*(float)kv[7];
    p += __shfl_xor(p, 1); p += __shfl_xor(p, 2);
    p += __shfl_xor(p, 4); p += __shfl_xor(p, 8);
    float wgt = (half == 0) ? __expf(p) : 0.f;      // only half 0 owns this edge
#pragma unroll
    for (int j = 0; j < 8; j++) n[j] += wgt*(float)vv[j];
    den += wgt;
  }
  // ultra-rare tail: degree > 64
  for (int i = beg + 64; i < end; i += 2){
    int e2 = i + half;
    int es = esrc[(e2 < end) ? e2 : i];
    const bf16_t* row = keve + ((size_t)(unsigned)es << 9);
    bf16x8 kv = *(const bf16x8*)(row + hl*8);
    bf16x8 vv = *(const bf16x8*)(row + 256 + hl*8);
    float p = qf[0]*(float)kv[0] + qf[1]*(float)kv[1]
            + qf[2]*(float)kv[2] + qf[3]*(float)kv[3]
            + qf[4]*(float)kv[4] + qf[5]*(float)kv[5]
            + qf[6]*(float)kv[6] + qf[7]*(float)kv[7];
    p += __shfl_xor(p, 1); p += __shfl_xor(p, 2);
    p += __shfl_xor(p, 4); p += __shfl_xor(p, 8);
    float wgt = (e2 < end) ? __expf(p) : 0.f;
#pragma unroll
    for (int j = 0; j < 8; j++) n[j] += wgt*(float)vv[j];
    den += wgt;
  }
  // merge the two half-wave edge streams
  den += __shfl_xor(den, 32);
#pragma unroll
  for (int j = 0; j < 8; j++) n[j] += __shfl_xor(n[j], 32);
  if (half == 0){
    float r = 1.f/(den + 1e-16f);
    bf16x8 o;
#pragma unroll
    for (int j = 0; j < 8; j++) o[j] = (bf16_t)(n[j]*r);
    *(bf16x8*)(agg + (size_t)dst*256 + hl*8) = o;
  }
}

extern "C" void kernel_launch(void* const* d_in, const int* in_sizes, int n_in,
                              void* d_out, int out_size, void* d_ws, size_t ws_size,
                              hipStream_t stream)
{
  (void)n_in; (void)out_size; (void)ws_size;
  const float* x_author    = (const float*)d_in[0];
  const float* x_paper     = (const float*)d_in[1];
  const int*   eb_src      = (const int*)d_in[4];
  const int*   eb_dst      = (const int*)d_in[5];
  const int*   input_nodes = (const int*)d_in[6];
  const float* W_in_a  = (const float*)d_in[7];
  const float* b_in_a  = (const float*)d_in[8];
  const float* W_in_p  = (const float*)d_in[9];
  const float* b_in_p  = (const float*)d_in[10];
  const float* Wkqv_a  = (const float*)d_in[11];
  const float* bkqv_a  = (const float*)d_in[12];
  const float* Wkqv_p  = (const float*)d_in[13];
  const float* bkqv_p  = (const float*)d_in[14];
  const float* Wk_rel_b= (const float*)d_in[17];
  const float* Wv_rel_b= (const float*)d_in[18];
  const float* p_b     = (const float*)d_in[20];
  const float* Wout_a  = (const float*)d_in[21];
  const float* bout_a  = (const float*)d_in[22];
  const float* skip_a  = (const float*)d_in[25];
  const float* W_dec   = (const float*)d_in[27];
  const float* b_dec   = (const float*)d_in[28];

  const int Na = in_sizes[0] / 128;
  const int Np = in_sizes[1] / 128;
  const int E  = in_sizes[4];
  const int NI = in_sizes[6];

  char* w = (char*)d_ws;
  auto alloc = [&](size_t bytes)->void*{
    void* p = (void*)w; w += (bytes + 255) & ~(size_t)255; return p;
  };
  bf16_t* xa_bf = (bf16_t*)alloc((size_t)Na*HID*2);
  bf16_t* xp_bf = (bf16_t*)alloc((size_t)Np*HID*2);
  bf16_t* qb    = (bf16_t*)alloc((size_t)Na*HID*2);  // reused as za after attention
  bf16_t* aggb  = (bf16_t*)alloc((size_t)Na*HID*2);
  bf16_t* zin   = (bf16_t*)alloc((size_t)NI*HID*2);
  bf16_t* Wt_in_a = (bf16_t*)alloc(128*HID*2);
  bf16_t* Wt_in_p = (bf16_t*)alloc(128*HID*2);
  bf16_t* Wt_q    = (bf16_t*)alloc(HID*HID*2);
  bf16_t* Wt_out  = (bf16_t*)alloc(HID*HID*2);
  bf16_t* Wt_dec  = (bf16_t*)alloc(HID*HID*2);
  bf16_t* Wkvt    = (bf16_t*)alloc((size_t)512*HID*2);
  float*  bkv     = (float*)alloc(512*4);
  int* deg    = (int*)alloc((size_t)Na*4);
  int* offs   = (int*)alloc((size_t)(Na+1)*4);
  int* cursor = (int*)alloc((size_t)Na*4);
  int* part   = (int*)alloc(1024);
  int* esrc   = (int*)alloc((size_t)E*4);

  // keve [Np,512] bf16 lives in d_out (dead before the final GEMM overwrites d_out)
  bf16_t* keve = (bf16_t*)d_out;
  bf16_t* zab  = qb;

  dim3 blk(256);

  // fused weight transposes (fp32 -> bf16, K-major)
  TW tw0 = { W_in_a,       Wt_in_a, 256, 128, 256 };
  TW tw1 = { W_in_p,       Wt_in_p, 256, 128, 256 };
  TW tw2 = { Wkqv_a + 256, Wt_q,    768, 256, 256 };
  TW tw3 = { Wout_a,       Wt_out,  256, 256, 256 };
  TW tw4 = { W_dec,        Wt_dec,  256, 256, 256 };
  prep_weights_k<<<dim3(8,8,5), dim3(32,8), 0, stream>>>(tw0, tw1, tw2, tw3, tw4);
  prep_fold_k<<<512, blk, 0, stream>>>(Wkqv_p, bkqv_p, Wk_rel_b, Wv_rel_b, Wkvt, bkv);
  hipMemsetAsync(deg, 0, (size_t)Na*4, stream);

  GArgs gz = {};  // placeholder

  // ---- batch 1: z0 xa-relu GEMM, z1 xp-relu GEMM, z2 hist (grid-stride) ----
  GArgs ga = { x_author, 128, Wt_in_a, 128, b_in_a, xa_bf, HID,
               Na, 256, 128, 1, 0, 1, nullptr, nullptr, nullptr, nullptr };
  GArgs gp = { x_paper,  128, Wt_in_p, 128, b_in_p, xp_bf, HID,
               Np, 256, 128, 1, 0, 1, nullptr, nullptr, nullptr, nullptr };
  gemm_batch_k<<<dim3(2, (Na+127)/128, 3), blk, 0, stream>>>(
      ga, gp, 1, eb_dst, nullptr, E, deg, nullptr);

  // ---- CSR scan chain ----
  int nb = (Na+255)/256;
  partial_sum_k<<<nb, blk, 0, stream>>>(deg, Na, part);
  scan_part_k<<<1, blk, 0, stream>>>(part, nb, offs+Na);
  scan_offs_k<<<nb, blk, 0, stream>>>(deg, Na, part, offs, cursor);

  // ---- batch 2: z0 q GEMM (x>=2 empty), z1 keve GEMM, z2 scatter (grid-stride) ----
  GArgs gq = { xa_bf, HID, Wt_q, HID, bkqv_a + 256, qb, HID,
               Na, 256, 256, 2, 0, 0, nullptr, p_b, nullptr, nullptr };
  GArgs gk = { xp_bf, HID, Wkvt, HID, bkv, keve, 512,
               Np, 512, 256, 0, 0, 0, nullptr, nullptr, nullptr, nullptr };
  gemm_batch_k<<<dim3(4, (Np+127)/128, 3), blk, 0, stream>>>(
      gq, gk, 2, eb_src, eb_dst, E, cursor, esrc);

  // ---- fused attention ----
  attn_fused_k<<<(Na+3)/4, blk, 0, stream>>>(qb, keve, offs, esrc, Na, aggb);

  // ---- za = g*(gelu(agg)@Wout + b) + (1-g)*xa ----
  GArgs gza = { aggb, HID, Wt_out, HID, bout_a, zab, HID,
                Na, 256, 256, 3, 1, 0, nullptr, nullptr, xa_bf, skip_a };
  gemm_batch_k<<<dim3(2, (Na+127)/128, 1), blk, 0, stream>>>(
      gza, gz, 0, nullptr, nullptr, 0, nullptr, nullptr);

  // ---- zin = za[input_nodes] @ W_dec + b ----
  GArgs gzin = { zab, HID, Wt_dec, HID, b_dec, zin, HID,
                 NI, 256, 256, 0, 0, 0, input_nodes, nullptr, nullptr, nullptr };
  gemm_batch_k<<<dim3(2, (NI+127)/128, 1), blk, 0, stream>>>(
      gzin, gz, 0, nullptr, nullptr, 0, nullptr, nullptr);

  // ---- out = sigmoid(zin @ za^T) ----
  GArgs gout = { zin, HID, zab, HID, nullptr, (float*)d_out, Na,
                 NI, Na, 256, 4, 0, 0, nullptr, nullptr, nullptr, nullptr };
  gemm_batch_k<<<dim3((Na+127)/128, (NI+127)/128, 1), blk, 0, stream>>>(
      gout, gz, 0, nullptr, nullptr, 0, nullptr, nullptr);
}